// Round 3
// baseline (117.824 us; speedup 1.0000x reference)
//
#include <hip/hip_runtime.h>

#define K   5
#define C   3
#define FC  75                   // K*K*C floats per pixel
#define GP  64                   // pixels per group = lanes per wave
#define SLABF 4864               // 1216 float4: 1200 data + 16 pad (clamp overhang)
#define GROUPS_PER_WAVE 16
#define NWAVEBLK 2               // waves per block

// 1,048,576 pixels = 16384 groups of 64.
// 512 blocks x 2 waves = 1024 persistent waves x 16 groups each.
// Per wave: private double-buffered LDS slab, 19x width-16 global_load_lds
// per group, counted s_waitcnt vmcnt(19) pipeline, zero barriers.
// LDS: 2 waves * 2 bufs * 4864 floats * 4B = 77,824 B -> 2 blocks/CU.

__global__ __launch_bounds__(128, 1)
void convolve_kernel(const float* __restrict__ img,
                     const float* __restrict__ filts,
                     float* __restrict__ out)
{
    __shared__ float sf[NWAVEBLK * 2 * SLABF];

    const int lane = threadIdx.x & 63;
    const int wave = threadIdx.x >> 6;

    float* sl0 = sf + (wave * 2 + 0) * SLABF;
    float* sl1 = sf + (wave * 2 + 1) * SLABF;

    const int wgid = blockIdx.x * NWAVEBLK + wave;
    const int g0   = wgid * GROUPS_PER_WAVE;

    // Stage one 64-pixel group's filters (4800 floats = 1200 float4) into a
    // wave-private slab. 19 full-wave width-16 loads; per-lane global index
    // clamped to 1199 (last 16 lanes of j=18 re-read a valid float4 into pad).
    auto stage = [&](float* slab, int g) {
        const float4* src4 = (const float4*)(filts + (size_t)g * (GP * FC));
        #pragma unroll
        for (int j = 0; j < 19; ++j) {
            int idx4 = j * 64 + lane;
            idx4 = idx4 > 1199 ? 1199 : idx4;     // clamp, no divergence
            __builtin_amdgcn_global_load_lds(
                (const __attribute__((address_space(1))) void*)(src4 + idx4),
                (__attribute__((address_space(3))) void*)(slab + j * 256),
                16, 0, 0);
        }
    };

    stage(sl0, g0);
    float* cur = sl0;
    float* nxt = sl1;

    #pragma unroll 1
    for (int k = 0; k < GROUPS_PER_WAVE; ++k) {
        if (k + 1 < GROUPS_PER_WAVE) {
            stage(nxt, g0 + k + 1);                           // 19 loads in flight
            asm volatile("s_waitcnt vmcnt(19)" ::: "memory"); // group k landed
        } else {
            asm volatile("s_waitcnt vmcnt(0)" ::: "memory");
        }
        __builtin_amdgcn_sched_barrier(0);  // rule #18: keep ds_reads below wait

        const int g  = g0 + k;
        const int p  = g * GP + lane;        // 64 consecutive pixels, same row
        const int b  = p >> 18;              // / (512*512)
        const int hw = p & ((1 << 18) - 1);
        const int h  = hw >> 9;
        const int w  = hw & 511;

        const float* fp   = cur + lane * FC; // lane stride 75 dwords -> 2/bank, free
        const float* imgb = img + (size_t)b * (512u * 512u * 3u);

        float a0 = 0.f, a1 = 0.f, a2 = 0.f;  // 3 chains vs FMA dep latency
        #pragma unroll
        for (int di = 0; di < K; ++di) {
            const int hh = h + di - 2;
            if ((unsigned)hh < 512u) {       // wave-uniform (h uniform per group)
                const float* row = imgb + (size_t)hh * (512 * 3);
                #pragma unroll
                for (int dj = 0; dj < K; ++dj) {
                    const int ww = w + dj - 2;
                    if ((unsigned)ww < 512u) {
                        const float* px = row + ww * 3;
                        const int fo = (di * K + dj) * C;
                        a0 += px[0] * fp[fo + 0];
                        a1 += px[1] * fp[fo + 1];
                        a2 += px[2] * fp[fo + 2];
                    }
                }
            }
        }
        out[p] = a0 + a1 + a2;

        float* t = cur; cur = nxt; nxt = t;
    }
}

extern "C" void kernel_launch(void* const* d_in, const int* in_sizes, int n_in,
                              void* d_out, int out_size, void* d_ws, size_t ws_size,
                              hipStream_t stream)
{
    const float* img   = (const float*)d_in[0];   // [4,512,512,3]  f32
    const float* filts = (const float*)d_in[1];   // [4,512,512,75] f32
    float* out         = (float*)d_out;           // [4,512,512]    f32

    // 16384 groups / 16 per wave = 1024 waves = 512 blocks of 128 threads
    convolve_kernel<<<512, 128, 0, stream>>>(img, filts, out);
}

// Round 5
// 106.874 us; speedup vs baseline: 1.1025x; 1.1025x over previous
//
#include <hip/hip_runtime.h>

#define K   5
#define C   3
#define FC  75                 // K*K*C floats per pixel
#define GP  64                 // pixels per group = lanes per wave
#define SLABF 4864             // slab floats: 1200 float4 data + 16 float4 pad
#define G   8                  // groups per wave
#define LASTG 16383            // 16384 groups total

typedef float f32x4 __attribute__((ext_vector_type(4)));

// 2048 blocks x 64 threads = 2048 persistent waves x 8 groups.
// Reg-staged depth-2 pipeline: while computing group k from the LDS slab,
// group k+1 sits landed in registers and group k+2's 19 loads are in flight.
// 19.5 KB LDS/block -> 8 blocks/CU; ~195 VGPR -> 2 waves/SIMD = 8 waves/CU.
// ~19 KB/wave continuously outstanding -> ~150 KB/CU (2x round-1 average).

__global__ __launch_bounds__(64, 2)
void convolve_kernel(const float* __restrict__ img,
                     const float* __restrict__ filts,
                     float* __restrict__ out)
{
    __shared__ float slab[SLABF];          // one wave per block, wave-private

    const int lane = threadIdx.x;          // 0..63

    // bijective XCD-chunked swizzle (2048 % 8 == 0): XCD x gets a contiguous
    // 256-block chunk = 128K consecutive pixels -> img slice fits its L2.
    const int wgid = ((int)blockIdx.x & 7) * 256 + ((int)blockIdx.x >> 3);
    const int g0   = wgid * G;

    f32x4 RA[19], RB[19];                  // static-indexed only (stay in VGPRs)

    // issue one group's 19 coalesced nontemporal float4 loads into regs
    auto issue = [&](f32x4* R, int g) {
        const f32x4* src4 = (const f32x4*)(filts + (size_t)g * (GP * FC));
        #pragma unroll
        for (int j = 0; j < 19; ++j) {
            int idx4 = j * 64 + lane;
            idx4 = idx4 > 1199 ? 1199 : idx4;      // clamp tail, keep 19 loads
            R[j] = __builtin_nontemporal_load(src4 + idx4);
        }
    };
    // commit a landed reg buffer into the slab (19 ds_write_b128, linear)
    auto commit = [&](const f32x4* R) {
        #pragma unroll
        for (int j = 0; j < 19; ++j)
            *(f32x4*)(slab + j * 256 + lane * 4) = R[j];
    };

    // prologue: fill pipeline 2 deep
    issue(RA, g0);
    {
        int g1 = g0 + 1; g1 = g1 > LASTG ? LASTG : g1;
        issue(RB, g1);
    }
    asm volatile("s_waitcnt vmcnt(19)" ::: "memory");   // RA landed
    __builtin_amdgcn_sched_barrier(0);
    commit(RA);
    asm volatile("s_waitcnt lgkmcnt(0)" ::: "memory");  // RA regs free, slab=g0
    __builtin_amdgcn_sched_barrier(0);

    #pragma unroll 1
    for (int k = 0; k < G; ++k) {
        // 1. refill freed reg buffer with group k+2 (always 19 loads, clamped)
        int gs = g0 + k + 2; gs = gs > LASTG ? LASTG : gs;
        if (k & 1) issue(RB, gs); else issue(RA, gs);

        // 2. newest 19 ops are exactly stage(k+2); drain everything older:
        //    stage(k+1) regs landed, img(k-1)/store(k-1) long done.
        asm volatile("s_waitcnt vmcnt(19)" ::: "memory");
        __builtin_amdgcn_sched_barrier(0);

        // 3. compute group k from slab
        const int g  = g0 + k;
        const int p  = g * GP + lane;        // 64 consecutive pixels, same row
        const int b  = p >> 18;
        const int hw = p & ((1 << 18) - 1);
        const int h  = hw >> 9;
        const int w  = hw & 511;

        const float* fp   = slab + lane * FC;   // stride 75 dw -> 2/bank, free
        const float* imgb = img + (size_t)b * (512u * 512u * 3u);

        float a0 = 0.f, a1 = 0.f, a2 = 0.f;
        #pragma unroll
        for (int di = 0; di < K; ++di) {
            const int hh = h + di - 2;
            if ((unsigned)hh < 512u) {           // wave-uniform (h uniform)
                const float* row = imgb + (size_t)hh * (512 * 3);
                #pragma unroll
                for (int dj = 0; dj < K; ++dj) {
                    const int ww = w + dj - 2;
                    if ((unsigned)ww < 512u) {
                        const float* px = row + ww * 3;
                        const int fo = (di * K + dj) * C;
                        a0 += px[0] * fp[fo + 0];
                        a1 += px[1] * fp[fo + 1];
                        a2 += px[2] * fp[fo + 2];
                    }
                }
            }
        }
        __builtin_nontemporal_store(a0 + a1 + a2, out + p);

        // 4. overwrite slab with group k+1 (DS ops in-order per wave, and the
        //    slab alias keeps ds_writes after step-3's ds_reads)
        __builtin_amdgcn_sched_barrier(0);
        if (k & 1) commit(RA); else commit(RB);
        asm volatile("s_waitcnt lgkmcnt(0)" ::: "memory");  // regs free for step 1
        __builtin_amdgcn_sched_barrier(0);
    }
}

extern "C" void kernel_launch(void* const* d_in, const int* in_sizes, int n_in,
                              void* d_out, int out_size, void* d_ws, size_t ws_size,
                              hipStream_t stream)
{
    const float* img   = (const float*)d_in[0];   // [4,512,512,3]  f32
    const float* filts = (const float*)d_in[1];   // [4,512,512,75] f32
    float* out         = (float*)d_out;           // [4,512,512]    f32

    // 16384 groups / 8 per wave = 2048 waves = 2048 blocks of 64 threads
    convolve_kernel<<<2048, 64, 0, stream>>>(img, filts, out);
}

// Round 6
// 79.533 us; speedup vs baseline: 1.4815x; 1.3438x over previous
//
#include <hip/hip_runtime.h>

#define K   5
#define C   3
#define FC  75                 // K*K*C floats per pixel
#define GP  64                 // pixels per block = lanes per wave
#define SLABF 4864             // 1216 float4: 1200 data + 16 pad for clamp tail

typedef float f32x4 __attribute__((ext_vector_type(4)));

// 16384 blocks x 64 threads: one wave = one 64-pixel group.
// Per block: 19x width-16 global_load_lds -> vmcnt(0) -> compute. No barrier
// (single wave), no prefetch during compute (so img-load waits drain nothing
// extra). 19.5 KB LDS -> 8 independent blocks/CU; uncorrelated stage/compute
// phases keep HBM read queue full (queueing, not pipelining).

__global__ __launch_bounds__(64, 2)
void convolve_kernel(const float* __restrict__ img,
                     const float* __restrict__ filts,
                     float* __restrict__ out)
{
    __shared__ float slab[SLABF];

    const int lane = threadIdx.x;          // 0..63

    // bijective XCD-chunked swizzle (16384 % 8 == 0): XCD x gets groups
    // [x*2048, (x+1)*2048) = 128K consecutive pixels -> ~1.6MB img slice in L2.
    const int g = ((int)blockIdx.x & 7) * 2048 + ((int)blockIdx.x >> 3);

    // ---- stage this group's 4800 filts floats (1200 float4) into LDS ----
    {
        const f32x4* src4 = (const f32x4*)(filts + (size_t)g * (GP * FC));
        #pragma unroll
        for (int j = 0; j < 19; ++j) {
            int idx4 = j * 64 + lane;
            idx4 = idx4 > 1199 ? 1199 : idx4;   // clamp tail (writes land in pad)
            __builtin_amdgcn_global_load_lds(
                (const __attribute__((address_space(1))) void*)(src4 + idx4),
                (__attribute__((address_space(3))) void*)(slab + j * 256),
                16, 0, 0);
        }
    }
    asm volatile("s_waitcnt vmcnt(0)" ::: "memory");
    __builtin_amdgcn_sched_barrier(0);      // rule #18: ds_reads stay below wait

    // ---- compute: one pixel per lane ----
    const int p  = g * GP + lane;           // 64 consecutive pixels, same row
    const int b  = p >> 18;                 // / (512*512)
    const int hw = p & ((1 << 18) - 1);
    const int h  = hw >> 9;
    const int w  = hw & 511;

    const float* fp   = slab + lane * FC;   // stride 75 dwords -> 2/bank, free
    const float* imgb = img + (size_t)b * (512u * 512u * 3u);

    float a0 = 0.f, a1 = 0.f, a2 = 0.f;     // 3 chains vs FMA dep latency
    #pragma unroll
    for (int di = 0; di < K; ++di) {
        const int hh = h + di - 2;
        if ((unsigned)hh < 512u) {           // wave-uniform (h uniform per group)
            const float* row = imgb + (size_t)hh * (512 * 3);
            #pragma unroll
            for (int dj = 0; dj < K; ++dj) {
                const int ww = w + dj - 2;
                if ((unsigned)ww < 512u) {
                    const float* px = row + ww * 3;
                    const int fo = (di * K + dj) * C;
                    a0 += px[0] * fp[fo + 0];
                    a1 += px[1] * fp[fo + 1];
                    a2 += px[2] * fp[fo + 2];
                }
            }
        }
    }
    out[p] = a0 + a1 + a2;
}

extern "C" void kernel_launch(void* const* d_in, const int* in_sizes, int n_in,
                              void* d_out, int out_size, void* d_ws, size_t ws_size,
                              hipStream_t stream)
{
    const float* img   = (const float*)d_in[0];   // [4,512,512,3]  f32
    const float* filts = (const float*)d_in[1];   // [4,512,512,75] f32
    float* out         = (float*)d_out;           // [4,512,512]    f32

    // 1,048,576 pixels / 64 per block = 16384 blocks of 64 threads
    convolve_kernel<<<16384, 64, 0, stream>>>(img, filts, out);
}